// Round 7
// baseline (408.469 us; speedup 1.0000x reference)
//
#include <hip/hip_runtime.h>
#include <hip/hip_bf16.h>
#include <math.h>

// GCN 2-layer: h = Ddst^-1/2 A (Dsrc^-1/2 x) W + b, relu between.
// R7: gemm1 restructured — A-rows are wave-exclusive, so A goes straight
// global->regs (16 independent dwordx4, one drain) instead of through LDS;
// B staged in 2 K-phases with reg-prefetch so barriers never wait on HBM
// (R6: 62us with HBM 15%/VALU 7%/MFMA 4% = barrier-latency-bound).
// spmm1: 4-deep index/gather batching (serial chain, avg deg 8).

#define F_IN  256
#define F_HID 128
#define F_CLS 40

#define RSZ 8192    // nodes per histogram range (32KB LDS of uint counters)
#define NSL 32      // edge slices

typedef __bf16 bf16_t;
typedef bf16_t bf16x8 __attribute__((ext_vector_type(8)));
typedef float floatx4 __attribute__((ext_vector_type(4)));

static __device__ __forceinline__ unsigned short f2b(float f) {
    __hip_bfloat16 h = __float2bfloat16(f);   // RNE
    return __builtin_bit_cast(unsigned short, h);
}
static __device__ __forceinline__ float b2f(unsigned short u) {
    return __uint_as_float((unsigned)u << 16);
}

// ---- histogram partials: block (r, sl, y) counts keys-in-range from slice --
__global__ __launch_bounds__(256) void hist_kernel(
    const int* __restrict__ src, const int* __restrict__ dst,
    unsigned* __restrict__ partial_s, unsigned* __restrict__ partial_d, int E)
{
    __shared__ unsigned h[RSZ];
    const int t = threadIdx.x;
    const int r  = blockIdx.x / NSL;
    const int sl = blockIdx.x % NSL;
    const int lo = r * RSZ;
    const int* __restrict__ keys = blockIdx.y ? dst : src;
    unsigned* __restrict__ part = blockIdx.y ? partial_d : partial_s;

    for (int i = t; i < RSZ; i += 256) h[i] = 0;
    __syncthreads();

    const int slice = (E + NSL - 1) / NSL;
    const int e0 = sl * slice;
    const int e1 = min(E, e0 + slice);

    int e = e0 + t;
    for (; e + 7 * 256 < e1; e += 8 * 256) {
        int k[8];
        #pragma unroll
        for (int i = 0; i < 8; ++i) k[i] = keys[e + i * 256];
        #pragma unroll
        for (int i = 0; i < 8; ++i) {
            unsigned kk = (unsigned)(k[i] - lo);
            if (kk < RSZ) atomicAdd(&h[kk], 1u);
        }
    }
    for (; e < e1; e += 256) {
        unsigned kk = (unsigned)(keys[e] - lo);
        if (kk < RSZ) atomicAdd(&h[kk], 1u);
    }
    __syncthreads();

    unsigned* dst_p = part + (size_t)blockIdx.x * RSZ;
    for (int i = t; i < RSZ; i += 256) dst_p[i] = h[i];
}

// ---- reduce partials -> cnt_dst + norms ------------------------------------
__global__ __launch_bounds__(256) void degnorm_kernel(
    const unsigned* __restrict__ partial_s, const unsigned* __restrict__ partial_d,
    int* __restrict__ cnt_dst, float* __restrict__ norm_src,
    float* __restrict__ norm_dst, int N)
{
    int i = blockIdx.x * 256 + threadIdx.x;
    if (i >= N) return;
    int r = i / RSZ;
    int off = i & (RSZ - 1);
    const unsigned* ps = partial_s + (size_t)r * NSL * RSZ + off;
    const unsigned* pd = partial_d + (size_t)r * NSL * RSZ + off;
    unsigned ss = 0, sd = 0;
    #pragma unroll
    for (int sl = 0; sl < NSL; ++sl) {
        ss += ps[(size_t)sl * RSZ];
        sd += pd[(size_t)sl * RSZ];
    }
    cnt_dst[i] = (int)sd;
    norm_src[i] = ss ? 1.0f / sqrtf((float)ss) : 0.0f;
    norm_dst[i] = sd ? 1.0f / sqrtf((float)sd) : 0.0f;
}

// ---- hierarchical exclusive scan over cnt_dst (1024 elems / block) ---------
__global__ __launch_bounds__(256) void scan1_kernel(const int* __restrict__ cnt,
                                                    int* __restrict__ row_off,
                                                    int* __restrict__ blk_sums, int N) {
    __shared__ int s[256];
    const int t = threadIdx.x;
    const int base = blockIdx.x * 1024 + t * 4;
    int v0 = (base + 0 < N) ? cnt[base + 0] : 0;
    int v1 = (base + 1 < N) ? cnt[base + 1] : 0;
    int v2 = (base + 2 < N) ? cnt[base + 2] : 0;
    int v3 = (base + 3 < N) ? cnt[base + 3] : 0;
    int local = v0 + v1 + v2 + v3;
    s[t] = local;
    __syncthreads();
    for (int off = 1; off < 256; off <<= 1) {
        int x = (t >= off) ? s[t - off] : 0;
        __syncthreads();
        s[t] += x;
        __syncthreads();
    }
    int excl = s[t] - local;
    if (t == 255) blk_sums[blockIdx.x] = s[t];
    if (base + 0 < N) row_off[base + 0] = excl;
    if (base + 1 < N) row_off[base + 1] = excl + v0;
    if (base + 2 < N) row_off[base + 2] = excl + v0 + v1;
    if (base + 3 < N) row_off[base + 3] = excl + v0 + v1 + v2;
}

__global__ __launch_bounds__(256) void scan2_kernel(int* __restrict__ blk_sums, int B) {
    __shared__ int s[256];
    const int t = threadIdx.x;
    int local = (t < B) ? blk_sums[t] : 0;
    s[t] = local;
    __syncthreads();
    for (int off = 1; off < 256; off <<= 1) {
        int x = (t >= off) ? s[t - off] : 0;
        __syncthreads();
        s[t] += x;
        __syncthreads();
    }
    if (t < B) blk_sums[t] = s[t] - local;   // exclusive
}

__global__ __launch_bounds__(256) void scan3_kernel(int* __restrict__ row_off,
                                                    int* __restrict__ cursor,
                                                    const int* __restrict__ blk_sums,
                                                    int N, int E) {
    const int t = threadIdx.x;
    const int base = blockIdx.x * 1024 + t * 4;
    const int add = blk_sums[blockIdx.x];
    #pragma unroll
    for (int i = 0; i < 4; ++i) {
        int idx = base + i;
        if (idx < N) {
            int v = row_off[idx] + add;
            row_off[idx] = v;
            cursor[idx] = v;
        }
    }
    if (blockIdx.x == 0 && t == 0) row_off[N] = E;
}

// ---- scatter edges into CSR (grouped by dst) -------------------------------
__global__ void scatter_kernel(const int* __restrict__ src, const int* __restrict__ dst,
                               int* __restrict__ cursor, int* __restrict__ csr_src, int E) {
    int e = blockIdx.x * blockDim.x + threadIdx.x;
    if (e < E) {
        int pos = atomicAdd(&cursor[dst[e]], 1);
        csr_src[pos] = src[e];
    }
}

// ---- pack W1 [256][128] fp32 -> W1t [128][256] bf16 (n-major, k contig) ----
__global__ __launch_bounds__(256) void pack_w1t_kernel(const float* __restrict__ W1,
                                                       __hip_bfloat16* __restrict__ W1t) {
    int idx = blockIdx.x * 256 + threadIdx.x;     // 32768 total
    int n = idx >> 8;
    int k = idx & 255;
    W1t[idx] = __float2bfloat16(W1[(size_t)k * F_HID + n]);
}

// ---- GEMM1 (MFMA): h1b[N,128] = bf16( (X*norm_src)bf16 @ W1bf16 ) ----------
// 256 thr = 4 waves, 64 rows/block. A: global->regs (wave-exclusive rows,
// 16 independent dwordx4, one drain). B: 2 K-phases in LDS, reg-prefetched.
__global__ __launch_bounds__(256) void gemm1_mfma_kernel(
    const float* __restrict__ X, const __hip_bfloat16* __restrict__ W1t,
    const float* __restrict__ norm_src, __hip_bfloat16* __restrict__ h1b, int N)
{
    // K-half buffer: 128 n-rows x 128 k + pad 12 -> row stride 280B (6 dw mod 32):
    // fragment reads (16 consecutive n-rows) hit 16 distinct banks.
    __shared__ __hip_bfloat16 Bs[128][140];
    const int t = threadIdx.x;
    const int node0 = blockIdx.x * 64;
    const int lane = t & 63;
    const int w = t >> 6;
    const int l15 = lane & 15;
    const int quad = lane >> 4;

    const int arow = node0 + w * 16 + l15;
    const bool valid = arow < N;

    // ---- A: all K=256 into regs ----
    float4 a_raw[16];
    const float* xp = X + (size_t)arow * F_IN + quad * 8;
    if (valid) {
        #pragma unroll
        for (int kc = 0; kc < 8; ++kc) {
            a_raw[kc * 2 + 0] = *(const float4*)(xp + kc * 32);
            a_raw[kc * 2 + 1] = *(const float4*)(xp + kc * 32 + 4);
        }
    } else {
        #pragma unroll
        for (int i = 0; i < 16; ++i) a_raw[i] = make_float4(0.f, 0.f, 0.f, 0.f);
    }
    const float ns = valid ? norm_src[arow] : 0.0f;

    // ---- B phase-0 into regs: thread t -> n = t>>1, half h = t&1 ----
    const int bn = t >> 1;
    const int bh = t & 1;
    const __hip_bfloat16* wp = W1t + (size_t)bn * F_IN + bh * 64;
    uint4 breg[8];
    #pragma unroll
    for (int i = 0; i < 8; ++i) breg[i] = *(const uint4*)(wp + i * 8);

    // ---- convert A to bf16 (x ns) ----
    bf16x8 ab[8];
    #pragma unroll
    for (int kc = 0; kc < 8; ++kc) {
        union { bf16x8 v; unsigned short u[8]; } cv;
        float4 lo = a_raw[kc * 2 + 0];
        float4 hi = a_raw[kc * 2 + 1];
        cv.u[0] = f2b(lo.x * ns); cv.u[1] = f2b(lo.y * ns);
        cv.u[2] = f2b(lo.z * ns); cv.u[3] = f2b(lo.w * ns);
        cv.u[4] = f2b(hi.x * ns); cv.u[5] = f2b(hi.y * ns);
        cv.u[6] = f2b(hi.z * ns); cv.u[7] = f2b(hi.w * ns);
        ab[kc] = cv.v;
    }

    // write B phase-0 to LDS, then prefetch phase-1 into regs
    #pragma unroll
    for (int i = 0; i < 8; ++i)
        *(uint4*)&Bs[bn][bh * 64 + i * 8] = breg[i];
    #pragma unroll
    for (int i = 0; i < 8; ++i) breg[i] = *(const uint4*)(wp + 128 + i * 8);
    __syncthreads();

    floatx4 acc[8] = {};
    #pragma unroll
    for (int kcl = 0; kcl < 4; ++kcl) {
        #pragma unroll
        for (int nt = 0; nt < 8; ++nt) {
            bf16x8 b = *(const bf16x8*)&Bs[nt * 16 + l15][kcl * 32 + quad * 8];
            acc[nt] = __builtin_amdgcn_mfma_f32_16x16x32_bf16(ab[kcl], b, acc[nt], 0, 0, 0);
        }
    }
    __syncthreads();
    #pragma unroll
    for (int i = 0; i < 8; ++i)
        *(uint4*)&Bs[bn][bh * 64 + i * 8] = breg[i];
    __syncthreads();
    #pragma unroll
    for (int kcl = 0; kcl < 4; ++kcl) {
        #pragma unroll
        for (int nt = 0; nt < 8; ++nt) {
            bf16x8 b = *(const bf16x8*)&Bs[nt * 16 + l15][kcl * 32 + quad * 8];
            acc[nt] = __builtin_amdgcn_mfma_f32_16x16x32_bf16(ab[4 + kcl], b, acc[nt], 0, 0, 0);
        }
    }

    // C/D: col = lane&15 (n), row = quad*4 + reg (m)
    #pragma unroll
    for (int nt = 0; nt < 8; ++nt) {
        #pragma unroll
        for (int r = 0; r < 4; ++r) {
            int node = node0 + w * 16 + quad * 4 + r;
            if (node < N)
                h1b[(size_t)node * F_HID + nt * 16 + l15] = __float2bfloat16(acc[nt][r]);
        }
    }
}

// ---- SpMM1 (CSR, bf16 gather): agg1[n,:] = sum h1b[csr_src,:] --------------
// 4-deep batched index+gather to break the serial index->gather chain.
__global__ __launch_bounds__(256) void spmm1_csr_kernel(
    const __hip_bfloat16* __restrict__ h1b, const int* __restrict__ row_off,
    const int* __restrict__ csr_src, float* __restrict__ agg1, int N)
{
    const int t = threadIdx.x;
    const int node = blockIdx.x * 8 + (t >> 5);
    if (node >= N) return;
    const int c = (t & 31) << 2;
    const int start = row_off[node];
    const int end = row_off[node + 1];
    float4 acc = make_float4(0.f, 0.f, 0.f, 0.f);
    int j = start;
    for (; j + 4 <= end; j += 4) {
        int s0 = csr_src[j + 0];
        int s1 = csr_src[j + 1];
        int s2 = csr_src[j + 2];
        int s3 = csr_src[j + 3];
        ushort4 u0 = *(const ushort4*)(h1b + (size_t)s0 * F_HID + c);
        ushort4 u1 = *(const ushort4*)(h1b + (size_t)s1 * F_HID + c);
        ushort4 u2 = *(const ushort4*)(h1b + (size_t)s2 * F_HID + c);
        ushort4 u3 = *(const ushort4*)(h1b + (size_t)s3 * F_HID + c);
        acc.x += b2f(u0.x) + b2f(u1.x) + b2f(u2.x) + b2f(u3.x);
        acc.y += b2f(u0.y) + b2f(u1.y) + b2f(u2.y) + b2f(u3.y);
        acc.z += b2f(u0.z) + b2f(u1.z) + b2f(u2.z) + b2f(u3.z);
        acc.w += b2f(u0.w) + b2f(u1.w) + b2f(u2.w) + b2f(u3.w);
    }
    for (; j < end; ++j) {
        int s = csr_src[j];
        ushort4 u = *(const ushort4*)(h1b + (size_t)s * F_HID + c);
        acc.x += b2f(u.x);
        acc.y += b2f(u.y);
        acc.z += b2f(u.z);
        acc.w += b2f(u.w);
    }
    *(float4*)(agg1 + (size_t)node * F_HID + c) = acc;
}

// ---- GEMM2: h2[N,40] = relu(agg1*norm_dst + b1)*norm_src @ W2[128,40] ------
__global__ __launch_bounds__(320) void gemm2_kernel(
    const float* __restrict__ agg1, const float* __restrict__ W2,
    const float* __restrict__ b1, const float* __restrict__ norm_src,
    const float* __restrict__ norm_dst, float* __restrict__ h2, int N)
{
    __shared__ float As[64][132];
    __shared__ float Ws[128][40];
    const int t = threadIdx.x;
    const int node0 = blockIdx.x * 64;

    #pragma unroll
    for (int i = 0; i < 4; ++i) {
        int f = t + 320 * i;
        int r = f / 10;
        int kk = (f % 10) * 4;
        *(float4*)&Ws[r][kk] = *(const float4*)(W2 + (size_t)r * F_CLS + kk);
    }
    for (int f = t; f < 2048; f += 320) {
        int r = f >> 5;
        int kk = (f & 31) << 2;
        int node = node0 + r;
        float4 v = make_float4(0.f, 0.f, 0.f, 0.f);
        if (node < N) {
            float4 a = *(const float4*)(agg1 + (size_t)node * F_HID + kk);
            float nd = norm_dst[node];
            float ns = norm_src[node];
            float4 bb = *(const float4*)(b1 + kk);
            v.x = fmaxf(fmaf(a.x, nd, bb.x), 0.f) * ns;
            v.y = fmaxf(fmaf(a.y, nd, bb.y), 0.f) * ns;
            v.z = fmaxf(fmaf(a.z, nd, bb.z), 0.f) * ns;
            v.w = fmaxf(fmaf(a.w, nd, bb.w), 0.f) * ns;
        }
        *(float4*)&As[r][kk] = v;
    }
    __syncthreads();

    const int col = t % 40;
    const int rowg = t / 40;
    float acc[8] = {};
    #pragma unroll 8
    for (int k = 0; k < F_HID; ++k) {
        float w = Ws[k][col];
        #pragma unroll
        for (int i = 0; i < 8; ++i)
            acc[i] = fmaf(As[rowg * 8 + i][k], w, acc[i]);
    }
    #pragma unroll
    for (int i = 0; i < 8; ++i) {
        int node = node0 + rowg * 8 + i;
        if (node < N) h2[(size_t)node * F_CLS + col] = acc[i];
    }
}

// ---- SpMM2 (CSR) + epilogue: out[n,:] = (sum h2[src,:])*norm_dst[n] + b2 ---
__global__ __launch_bounds__(256) void spmm2_csr_kernel(
    const float* __restrict__ h2, const int* __restrict__ row_off,
    const int* __restrict__ csr_src, const float* __restrict__ norm_dst,
    const float* __restrict__ b2, float* __restrict__ out, int N)
{
    const int t = threadIdx.x;
    const int node = blockIdx.x * 16 + (t >> 4);
    const int lane = t & 15;
    if (node >= N || lane >= 10) return;
    const int c = lane << 2;
    const int start = row_off[node];
    const int end = row_off[node + 1];
    float4 acc = make_float4(0.f, 0.f, 0.f, 0.f);
    int j = start;
    for (; j + 4 <= end; j += 4) {
        int s0 = csr_src[j + 0];
        int s1 = csr_src[j + 1];
        int s2 = csr_src[j + 2];
        int s3 = csr_src[j + 3];
        float4 v0 = *(const float4*)(h2 + (size_t)s0 * F_CLS + c);
        float4 v1 = *(const float4*)(h2 + (size_t)s1 * F_CLS + c);
        float4 v2 = *(const float4*)(h2 + (size_t)s2 * F_CLS + c);
        float4 v3 = *(const float4*)(h2 + (size_t)s3 * F_CLS + c);
        acc.x += v0.x + v1.x + v2.x + v3.x;
        acc.y += v0.y + v1.y + v2.y + v3.y;
        acc.z += v0.z + v1.z + v2.z + v3.z;
        acc.w += v0.w + v1.w + v2.w + v3.w;
    }
    for (; j < end; ++j) {
        int s = csr_src[j];
        float4 v = *(const float4*)(h2 + (size_t)s * F_CLS + c);
        acc.x += v.x; acc.y += v.y; acc.z += v.z; acc.w += v.w;
    }
    float nd = norm_dst[node];
    float4 bb = *(const float4*)(b2 + c);
    float4 r;
    r.x = fmaf(acc.x, nd, bb.x);
    r.y = fmaf(acc.y, nd, bb.y);
    r.z = fmaf(acc.z, nd, bb.z);
    r.w = fmaf(acc.w, nd, bb.w);
    *(float4*)(out + (size_t)node * F_CLS + c) = r;
}

extern "C" void kernel_launch(void* const* d_in, const int* in_sizes, int n_in,
                              void* d_out, int out_size, void* d_ws, size_t ws_size,
                              hipStream_t stream) {
    const float* X   = (const float*)d_in[0];
    const int*   src = (const int*)d_in[1];
    const int*   dst = (const int*)d_in[2];
    const float* W1  = (const float*)d_in[3];
    const float* b1  = (const float*)d_in[4];
    const float* W2  = (const float*)d_in[5];
    const float* b2  = (const float*)d_in[6];
    float* out = (float*)d_out;

    const int N = in_sizes[0] / F_IN;
    const int E = in_sizes[1];
    const int NB = (N + 1023) / 1024;     // scan blocks (<= 256)
    const int NR = (N + RSZ - 1) / RSZ;   // histogram ranges

    // workspace layout — keep every array 16B-aligned
    char* w = (char*)d_ws;
    int*   cnt_dst  = (int*)w;                      w += (size_t)N * 4;
    int*   row_off  = (int*)w;                      w += (size_t)(N + 4) * 4;
    int*   cursor   = (int*)w;                      w += (size_t)N * 4;
    int*   blk_sums = (int*)w;                      w += 256 * 4;
    int*   csr_src  = (int*)w;                      w += (size_t)E * 4;
    float* norm_src = (float*)w;                    w += (size_t)N * 4;
    float* norm_dst = (float*)w;                    w += (size_t)N * 4;
    float* agg1     = (float*)w;                    w += (size_t)N * F_HID * 4;
    float* h2       = (float*)w;                    w += (size_t)N * F_CLS * 4;
    __hip_bfloat16* W1t = (__hip_bfloat16*)w;       w += (size_t)F_HID * F_IN * 2;
    __hip_bfloat16* h1b = (__hip_bfloat16*)w;       w += (size_t)N * F_HID * 2;

    // histogram partials alias agg1+h2 region (dead until spmm1 writes agg1)
    unsigned* partial_s = (unsigned*)agg1;                        // NR*NSL*RSZ
    unsigned* partial_d = partial_s + (size_t)NR * NSL * RSZ;     // NR*NSL*RSZ

    hist_kernel<<<dim3(NR * NSL, 2), 256, 0, stream>>>(src, dst, partial_s, partial_d, E);
    degnorm_kernel<<<(N + 255) / 256, 256, 0, stream>>>(partial_s, partial_d,
                                                        cnt_dst, norm_src, norm_dst, N);

    scan1_kernel<<<NB, 256, 0, stream>>>(cnt_dst, row_off, blk_sums, N);
    scan2_kernel<<<1, 256, 0, stream>>>(blk_sums, NB);
    scan3_kernel<<<NB, 256, 0, stream>>>(row_off, cursor, blk_sums, N, E);
    scatter_kernel<<<(E + 255) / 256, 256, 0, stream>>>(src, dst, cursor, csr_src, E);

    pack_w1t_kernel<<<(F_HID * F_IN) / 256, 256, 0, stream>>>(W1, W1t);

    gemm1_mfma_kernel<<<(N + 63) / 64, 256, 0, stream>>>(X, W1t, norm_src, h1b, N);

    spmm1_csr_kernel<<<(N + 7) / 8, 256, 0, stream>>>(h1b, row_off, csr_src, agg1, N);

    gemm2_kernel<<<(N + 63) / 64, 320, 0, stream>>>(agg1, W2, b1, norm_src, norm_dst, h2, N);

    spmm2_csr_kernel<<<(N + 15) / 16, 256, 0, stream>>>(h2, row_off, csr_src, norm_dst, b2, out, N);
}

// Round 8
// 384.684 us; speedup vs baseline: 1.0618x; 1.0618x over previous
//
#include <hip/hip_runtime.h>
#include <hip/hip_bf16.h>
#include <math.h>

// GCN 2-layer: h = Ddst^-1/2 A (Dsrc^-1/2 x) W + b, relu between.
// R8: gemm1 = chunked pipeline. R7 spilled (VGPR 64, +50MB scratch r/w):
// holding all K=256 of A in regs blew the budget. Now BK=64 chunks:
// A per-chunk in regs (wave-exclusive rows, no LDS), B double-buffered in
// LDS (R6's proven stride-72 layout), ONE barrier/iter, prefetch issued
// AFTER the barrier so its vmcnt(0) drain only hits loads a full MFMA
// section old. __launch_bounds__(256,4) caps VGPR at 128.

#define F_IN  256
#define F_HID 128
#define F_CLS 40

#define RSZ 8192    // nodes per histogram range (32KB LDS of uint counters)
#define NSL 32      // edge slices

typedef __bf16 bf16_t;
typedef bf16_t bf16x8 __attribute__((ext_vector_type(8)));
typedef float floatx4 __attribute__((ext_vector_type(4)));

static __device__ __forceinline__ unsigned short f2b(float f) {
    __hip_bfloat16 h = __float2bfloat16(f);   // RNE
    return __builtin_bit_cast(unsigned short, h);
}
static __device__ __forceinline__ float b2f(unsigned short u) {
    return __uint_as_float((unsigned)u << 16);
}

// ---- histogram partials: block (r, sl, y) counts keys-in-range from slice --
__global__ __launch_bounds__(256) void hist_kernel(
    const int* __restrict__ src, const int* __restrict__ dst,
    unsigned* __restrict__ partial_s, unsigned* __restrict__ partial_d, int E)
{
    __shared__ unsigned h[RSZ];
    const int t = threadIdx.x;
    const int r  = blockIdx.x / NSL;
    const int sl = blockIdx.x % NSL;
    const int lo = r * RSZ;
    const int* __restrict__ keys = blockIdx.y ? dst : src;
    unsigned* __restrict__ part = blockIdx.y ? partial_d : partial_s;

    for (int i = t; i < RSZ; i += 256) h[i] = 0;
    __syncthreads();

    const int slice = (E + NSL - 1) / NSL;
    const int e0 = sl * slice;
    const int e1 = min(E, e0 + slice);

    int e = e0 + t;
    for (; e + 7 * 256 < e1; e += 8 * 256) {
        int k[8];
        #pragma unroll
        for (int i = 0; i < 8; ++i) k[i] = keys[e + i * 256];
        #pragma unroll
        for (int i = 0; i < 8; ++i) {
            unsigned kk = (unsigned)(k[i] - lo);
            if (kk < RSZ) atomicAdd(&h[kk], 1u);
        }
    }
    for (; e < e1; e += 256) {
        unsigned kk = (unsigned)(keys[e] - lo);
        if (kk < RSZ) atomicAdd(&h[kk], 1u);
    }
    __syncthreads();

    unsigned* dst_p = part + (size_t)blockIdx.x * RSZ;
    for (int i = t; i < RSZ; i += 256) dst_p[i] = h[i];
}

// ---- reduce partials -> cnt_dst + norms ------------------------------------
__global__ __launch_bounds__(256) void degnorm_kernel(
    const unsigned* __restrict__ partial_s, const unsigned* __restrict__ partial_d,
    int* __restrict__ cnt_dst, float* __restrict__ norm_src,
    float* __restrict__ norm_dst, int N)
{
    int i = blockIdx.x * 256 + threadIdx.x;
    if (i >= N) return;
    int r = i / RSZ;
    int off = i & (RSZ - 1);
    const unsigned* ps = partial_s + (size_t)r * NSL * RSZ + off;
    const unsigned* pd = partial_d + (size_t)r * NSL * RSZ + off;
    unsigned ss = 0, sd = 0;
    #pragma unroll
    for (int sl = 0; sl < NSL; ++sl) {
        ss += ps[(size_t)sl * RSZ];
        sd += pd[(size_t)sl * RSZ];
    }
    cnt_dst[i] = (int)sd;
    norm_src[i] = ss ? 1.0f / sqrtf((float)ss) : 0.0f;
    norm_dst[i] = sd ? 1.0f / sqrtf((float)sd) : 0.0f;
}

// ---- hierarchical exclusive scan over cnt_dst (1024 elems / block) ---------
__global__ __launch_bounds__(256) void scan1_kernel(const int* __restrict__ cnt,
                                                    int* __restrict__ row_off,
                                                    int* __restrict__ blk_sums, int N) {
    __shared__ int s[256];
    const int t = threadIdx.x;
    const int base = blockIdx.x * 1024 + t * 4;
    int v0 = (base + 0 < N) ? cnt[base + 0] : 0;
    int v1 = (base + 1 < N) ? cnt[base + 1] : 0;
    int v2 = (base + 2 < N) ? cnt[base + 2] : 0;
    int v3 = (base + 3 < N) ? cnt[base + 3] : 0;
    int local = v0 + v1 + v2 + v3;
    s[t] = local;
    __syncthreads();
    for (int off = 1; off < 256; off <<= 1) {
        int x = (t >= off) ? s[t - off] : 0;
        __syncthreads();
        s[t] += x;
        __syncthreads();
    }
    int excl = s[t] - local;
    if (t == 255) blk_sums[blockIdx.x] = s[t];
    if (base + 0 < N) row_off[base + 0] = excl;
    if (base + 1 < N) row_off[base + 1] = excl + v0;
    if (base + 2 < N) row_off[base + 2] = excl + v0 + v1;
    if (base + 3 < N) row_off[base + 3] = excl + v0 + v1 + v2;
}

__global__ __launch_bounds__(256) void scan2_kernel(int* __restrict__ blk_sums, int B) {
    __shared__ int s[256];
    const int t = threadIdx.x;
    int local = (t < B) ? blk_sums[t] : 0;
    s[t] = local;
    __syncthreads();
    for (int off = 1; off < 256; off <<= 1) {
        int x = (t >= off) ? s[t - off] : 0;
        __syncthreads();
        s[t] += x;
        __syncthreads();
    }
    if (t < B) blk_sums[t] = s[t] - local;   // exclusive
}

__global__ __launch_bounds__(256) void scan3_kernel(int* __restrict__ row_off,
                                                    int* __restrict__ cursor,
                                                    const int* __restrict__ blk_sums,
                                                    int N, int E) {
    const int t = threadIdx.x;
    const int base = blockIdx.x * 1024 + t * 4;
    const int add = blk_sums[blockIdx.x];
    #pragma unroll
    for (int i = 0; i < 4; ++i) {
        int idx = base + i;
        if (idx < N) {
            int v = row_off[idx] + add;
            row_off[idx] = v;
            cursor[idx] = v;
        }
    }
    if (blockIdx.x == 0 && t == 0) row_off[N] = E;
}

// ---- scatter edges into CSR (grouped by dst) -------------------------------
__global__ void scatter_kernel(const int* __restrict__ src, const int* __restrict__ dst,
                               int* __restrict__ cursor, int* __restrict__ csr_src, int E) {
    int e = blockIdx.x * blockDim.x + threadIdx.x;
    if (e < E) {
        int pos = atomicAdd(&cursor[dst[e]], 1);
        csr_src[pos] = src[e];
    }
}

// ---- pack W1 [256][128] fp32 -> W1t [128][256] bf16 (n-major, k contig) ----
__global__ __launch_bounds__(256) void pack_w1t_kernel(const float* __restrict__ W1,
                                                       __hip_bfloat16* __restrict__ W1t) {
    int idx = blockIdx.x * 256 + threadIdx.x;     // 32768 total
    int n = idx >> 8;
    int k = idx & 255;
    W1t[idx] = __float2bfloat16(W1[(size_t)k * F_HID + n]);
}

// ---- GEMM1 (MFMA): h1b[N,128] = bf16( (X*norm_src)bf16 @ W1bf16 ) ----------
// 256 thr = 4 waves, 64 rows/block. BK=64 chunks: A per-chunk in regs
// (wave-exclusive rows), B double-buffered in LDS, one barrier per chunk,
// prefetch issued after the barrier (drain only hits loads one MFMA-section
// old).
__global__ __launch_bounds__(256, 4) void gemm1_mfma_kernel(
    const float* __restrict__ X, const __hip_bfloat16* __restrict__ W1t,
    const float* __restrict__ norm_src, __hip_bfloat16* __restrict__ h1b, int N)
{
    __shared__ __hip_bfloat16 Bs[2][128][72];   // 2 x 18432 B; stride 144B (R6 layout)
    const int t = threadIdx.x;
    const int node0 = blockIdx.x * 64;
    const int lane = t & 63;
    const int w = t >> 6;
    const int l15 = lane & 15;
    const int quad = lane >> 4;

    const int arow = node0 + w * 16 + l15;
    const bool valid = arow < N;
    const int arow_c = valid ? arow : (N - 1);
    const float ns = valid ? norm_src[arow] : 0.0f;

    // B staging role: row n = t>>1, k-half h = t&1 (32 bf16 = 4 uint4)
    const int bn = t >> 1;
    const int bh = t & 1;
    const __hip_bfloat16* wp = W1t + (size_t)bn * F_IN + bh * 32;
    const float* xp = X + (size_t)arow_c * F_IN + quad * 8;

    uint4  breg[4];
    float4 araw[4];

    // preload chunk 0
    #pragma unroll
    for (int i = 0; i < 4; ++i) breg[i] = *(const uint4*)(wp + i * 8);
    araw[0] = *(const float4*)(xp + 0);
    araw[1] = *(const float4*)(xp + 4);
    araw[2] = *(const float4*)(xp + 32);
    araw[3] = *(const float4*)(xp + 36);

    floatx4 acc[8] = {};

    #pragma unroll
    for (int c = 0; c < 4; ++c) {
        // 1) write B chunk c -> LDS (waits vmcnt on breg)
        #pragma unroll
        for (int j = 0; j < 4; ++j)
            *(uint4*)&Bs[c & 1][bn][bh * 32 + j * 8] = breg[j];
        // 2) one barrier (drains everything; prefetches were issued an MFMA
        //    section ago, so this wait is cheap in steady state)
        __syncthreads();
        // 3) convert A chunk c (loads already drained)
        bf16x8 ab0, ab1;
        {
            union { bf16x8 v; unsigned short u[8]; } cv;
            cv.u[0] = f2b(araw[0].x * ns); cv.u[1] = f2b(araw[0].y * ns);
            cv.u[2] = f2b(araw[0].z * ns); cv.u[3] = f2b(araw[0].w * ns);
            cv.u[4] = f2b(araw[1].x * ns); cv.u[5] = f2b(araw[1].y * ns);
            cv.u[6] = f2b(araw[1].z * ns); cv.u[7] = f2b(araw[1].w * ns);
            ab0 = cv.v;
            cv.u[0] = f2b(araw[2].x * ns); cv.u[1] = f2b(araw[2].y * ns);
            cv.u[2] = f2b(araw[2].z * ns); cv.u[3] = f2b(araw[2].w * ns);
            cv.u[4] = f2b(araw[3].x * ns); cv.u[5] = f2b(araw[3].y * ns);
            cv.u[6] = f2b(araw[3].z * ns); cv.u[7] = f2b(araw[3].w * ns);
            ab1 = cv.v;
        }
        // 4) prefetch chunk c+1 (overlaps the MFMA section below)
        if (c < 3) {
            #pragma unroll
            for (int i = 0; i < 4; ++i)
                breg[i] = *(const uint4*)(wp + (c + 1) * 64 + i * 8);
            araw[0] = *(const float4*)(xp + (c + 1) * 64 + 0);
            araw[1] = *(const float4*)(xp + (c + 1) * 64 + 4);
            araw[2] = *(const float4*)(xp + (c + 1) * 64 + 32);
            araw[3] = *(const float4*)(xp + (c + 1) * 64 + 36);
        }
        // 5) MFMA on LDS buf[c&1]
        #pragma unroll
        for (int nt = 0; nt < 8; ++nt) {
            bf16x8 b = *(const bf16x8*)&Bs[c & 1][nt * 16 + l15][quad * 8];
            acc[nt] = __builtin_amdgcn_mfma_f32_16x16x32_bf16(ab0, b, acc[nt], 0, 0, 0);
        }
        #pragma unroll
        for (int nt = 0; nt < 8; ++nt) {
            bf16x8 b = *(const bf16x8*)&Bs[c & 1][nt * 16 + l15][32 + quad * 8];
            acc[nt] = __builtin_amdgcn_mfma_f32_16x16x32_bf16(ab1, b, acc[nt], 0, 0, 0);
        }
        // no trailing barrier: double buffer + the c+1 barrier protect reuse
    }

    // C/D: col = lane&15 (n), row = quad*4 + reg (m)
    #pragma unroll
    for (int nt = 0; nt < 8; ++nt) {
        #pragma unroll
        for (int r = 0; r < 4; ++r) {
            int node = node0 + w * 16 + quad * 4 + r;
            if (node < N)
                h1b[(size_t)node * F_HID + nt * 16 + l15] = __float2bfloat16(acc[nt][r]);
        }
    }
}

// ---- SpMM1 (CSR, bf16 gather): agg1[n,:] = sum h1b[csr_src,:] --------------
__global__ __launch_bounds__(256) void spmm1_csr_kernel(
    const __hip_bfloat16* __restrict__ h1b, const int* __restrict__ row_off,
    const int* __restrict__ csr_src, float* __restrict__ agg1, int N)
{
    const int t = threadIdx.x;
    const int node = blockIdx.x * 8 + (t >> 5);
    if (node >= N) return;
    const int c = (t & 31) << 2;
    const int start = row_off[node];
    const int end = row_off[node + 1];
    float4 acc = make_float4(0.f, 0.f, 0.f, 0.f);
    int j = start;
    for (; j + 4 <= end; j += 4) {
        int s0 = csr_src[j + 0];
        int s1 = csr_src[j + 1];
        int s2 = csr_src[j + 2];
        int s3 = csr_src[j + 3];
        ushort4 u0 = *(const ushort4*)(h1b + (size_t)s0 * F_HID + c);
        ushort4 u1 = *(const ushort4*)(h1b + (size_t)s1 * F_HID + c);
        ushort4 u2 = *(const ushort4*)(h1b + (size_t)s2 * F_HID + c);
        ushort4 u3 = *(const ushort4*)(h1b + (size_t)s3 * F_HID + c);
        acc.x += b2f(u0.x) + b2f(u1.x) + b2f(u2.x) + b2f(u3.x);
        acc.y += b2f(u0.y) + b2f(u1.y) + b2f(u2.y) + b2f(u3.y);
        acc.z += b2f(u0.z) + b2f(u1.z) + b2f(u2.z) + b2f(u3.z);
        acc.w += b2f(u0.w) + b2f(u1.w) + b2f(u2.w) + b2f(u3.w);
    }
    for (; j < end; ++j) {
        int s = csr_src[j];
        ushort4 u = *(const ushort4*)(h1b + (size_t)s * F_HID + c);
        acc.x += b2f(u.x);
        acc.y += b2f(u.y);
        acc.z += b2f(u.z);
        acc.w += b2f(u.w);
    }
    *(float4*)(agg1 + (size_t)node * F_HID + c) = acc;
}

// ---- GEMM2: h2[N,40] = relu(agg1*norm_dst + b1)*norm_src @ W2[128,40] ------
__global__ __launch_bounds__(320) void gemm2_kernel(
    const float* __restrict__ agg1, const float* __restrict__ W2,
    const float* __restrict__ b1, const float* __restrict__ norm_src,
    const float* __restrict__ norm_dst, float* __restrict__ h2, int N)
{
    __shared__ float As[64][132];
    __shared__ float Ws[128][40];
    const int t = threadIdx.x;
    const int node0 = blockIdx.x * 64;

    #pragma unroll
    for (int i = 0; i < 4; ++i) {
        int f = t + 320 * i;
        int r = f / 10;
        int kk = (f % 10) * 4;
        *(float4*)&Ws[r][kk] = *(const float4*)(W2 + (size_t)r * F_CLS + kk);
    }
    for (int f = t; f < 2048; f += 320) {
        int r = f >> 5;
        int kk = (f & 31) << 2;
        int node = node0 + r;
        float4 v = make_float4(0.f, 0.f, 0.f, 0.f);
        if (node < N) {
            float4 a = *(const float4*)(agg1 + (size_t)node * F_HID + kk);
            float nd = norm_dst[node];
            float ns = norm_src[node];
            float4 bb = *(const float4*)(b1 + kk);
            v.x = fmaxf(fmaf(a.x, nd, bb.x), 0.f) * ns;
            v.y = fmaxf(fmaf(a.y, nd, bb.y), 0.f) * ns;
            v.z = fmaxf(fmaf(a.z, nd, bb.z), 0.f) * ns;
            v.w = fmaxf(fmaf(a.w, nd, bb.w), 0.f) * ns;
        }
        *(float4*)&As[r][kk] = v;
    }
    __syncthreads();

    const int col = t % 40;
    const int rowg = t / 40;
    float acc[8] = {};
    #pragma unroll 8
    for (int k = 0; k < F_HID; ++k) {
        float w = Ws[k][col];
        #pragma unroll
        for (int i = 0; i < 8; ++i)
            acc[i] = fmaf(As[rowg * 8 + i][k], w, acc[i]);
    }
    #pragma unroll
    for (int i = 0; i < 8; ++i) {
        int node = node0 + rowg * 8 + i;
        if (node < N) h2[(size_t)node * F_CLS + col] = acc[i];
    }
}

// ---- SpMM2 (CSR) + epilogue: out[n,:] = (sum h2[src,:])*norm_dst[n] + b2 ---
__global__ __launch_bounds__(256) void spmm2_csr_kernel(
    const float* __restrict__ h2, const int* __restrict__ row_off,
    const int* __restrict__ csr_src, const float* __restrict__ norm_dst,
    const float* __restrict__ b2, float* __restrict__ out, int N)
{
    const int t = threadIdx.x;
    const int node = blockIdx.x * 16 + (t >> 4);
    const int lane = t & 15;
    if (node >= N || lane >= 10) return;
    const int c = lane << 2;
    const int start = row_off[node];
    const int end = row_off[node + 1];
    float4 acc = make_float4(0.f, 0.f, 0.f, 0.f);
    int j = start;
    for (; j + 4 <= end; j += 4) {
        int s0 = csr_src[j + 0];
        int s1 = csr_src[j + 1];
        int s2 = csr_src[j + 2];
        int s3 = csr_src[j + 3];
        float4 v0 = *(const float4*)(h2 + (size_t)s0 * F_CLS + c);
        float4 v1 = *(const float4*)(h2 + (size_t)s1 * F_CLS + c);
        float4 v2 = *(const float4*)(h2 + (size_t)s2 * F_CLS + c);
        float4 v3 = *(const float4*)(h2 + (size_t)s3 * F_CLS + c);
        acc.x += v0.x + v1.x + v2.x + v3.x;
        acc.y += v0.y + v1.y + v2.y + v3.y;
        acc.z += v0.z + v1.z + v2.z + v3.z;
        acc.w += v0.w + v1.w + v2.w + v3.w;
    }
    for (; j < end; ++j) {
        int s = csr_src[j];
        float4 v = *(const float4*)(h2 + (size_t)s * F_CLS + c);
        acc.x += v.x; acc.y += v.y; acc.z += v.z; acc.w += v.w;
    }
    float nd = norm_dst[node];
    float4 bb = *(const float4*)(b2 + c);
    float4 r;
    r.x = fmaf(acc.x, nd, bb.x);
    r.y = fmaf(acc.y, nd, bb.y);
    r.z = fmaf(acc.z, nd, bb.z);
    r.w = fmaf(acc.w, nd, bb.w);
    *(float4*)(out + (size_t)node * F_CLS + c) = r;
}

extern "C" void kernel_launch(void* const* d_in, const int* in_sizes, int n_in,
                              void* d_out, int out_size, void* d_ws, size_t ws_size,
                              hipStream_t stream) {
    const float* X   = (const float*)d_in[0];
    const int*   src = (const int*)d_in[1];
    const int*   dst = (const int*)d_in[2];
    const float* W1  = (const float*)d_in[3];
    const float* b1  = (const float*)d_in[4];
    const float* W2  = (const float*)d_in[5];
    const float* b2  = (const float*)d_in[6];
    float* out = (float*)d_out;

    const int N = in_sizes[0] / F_IN;
    const int E = in_sizes[1];
    const int NB = (N + 1023) / 1024;     // scan blocks (<= 256)
    const int NR = (N + RSZ - 1) / RSZ;   // histogram ranges

    // workspace layout — keep every array 16B-aligned
    char* w = (char*)d_ws;
    int*   cnt_dst  = (int*)w;                      w += (size_t)N * 4;
    int*   row_off  = (int*)w;                      w += (size_t)(N + 4) * 4;
    int*   cursor   = (int*)w;                      w += (size_t)N * 4;
    int*   blk_sums = (int*)w;                      w += 256 * 4;
    int*   csr_src  = (int*)w;                      w += (size_t)E * 4;
    float* norm_src = (float*)w;                    w += (size_t)N * 4;
    float* norm_dst = (float*)w;                    w += (size_t)N * 4;
    float* agg1     = (float*)w;                    w += (size_t)N * F_HID * 4;
    float* h2       = (float*)w;                    w += (size_t)N * F_CLS * 4;
    __hip_bfloat16* W1t = (__hip_bfloat16*)w;       w += (size_t)F_HID * F_IN * 2;
    __hip_bfloat16* h1b = (__hip_bfloat16*)w;       w += (size_t)N * F_HID * 2;

    // histogram partials alias agg1+h2 region (dead until spmm1 writes agg1)
    unsigned* partial_s = (unsigned*)agg1;                        // NR*NSL*RSZ
    unsigned* partial_d = partial_s + (size_t)NR * NSL * RSZ;     // NR*NSL*RSZ

    hist_kernel<<<dim3(NR * NSL, 2), 256, 0, stream>>>(src, dst, partial_s, partial_d, E);
    degnorm_kernel<<<(N + 255) / 256, 256, 0, stream>>>(partial_s, partial_d,
                                                        cnt_dst, norm_src, norm_dst, N);

    scan1_kernel<<<NB, 256, 0, stream>>>(cnt_dst, row_off, blk_sums, N);
    scan2_kernel<<<1, 256, 0, stream>>>(blk_sums, NB);
    scan3_kernel<<<NB, 256, 0, stream>>>(row_off, cursor, blk_sums, N, E);
    scatter_kernel<<<(E + 255) / 256, 256, 0, stream>>>(src, dst, cursor, csr_src, E);

    pack_w1t_kernel<<<(F_HID * F_IN) / 256, 256, 0, stream>>>(W1, W1t);

    gemm1_mfma_kernel<<<(N + 63) / 64, 256, 0, stream>>>(X, W1t, norm_src, h1b, N);

    spmm1_csr_kernel<<<(N + 7) / 8, 256, 0, stream>>>(h1b, row_off, csr_src, agg1, N);

    gemm2_kernel<<<(N + 63) / 64, 320, 0, stream>>>(agg1, W2, b1, norm_src, norm_dst, h2, N);

    spmm2_csr_kernel<<<(N + 15) / 16, 256, 0, stream>>>(h2, row_off, csr_src, norm_dst, b2, out, N);
}

// Round 9
// 373.517 us; speedup vs baseline: 1.0936x; 1.0299x over previous
//
#include <hip/hip_runtime.h>
#include <hip/hip_bf16.h>
#include <math.h>

// GCN 2-layer: h = Ddst^-1/2 A (Dsrc^-1/2 x) W + b, relu between.
// R9: (1) atomic-free CSR scatter — slice-prefix over hist partials gives
// absolute cursors; scatter replays slices with LDS cursors + plain stores
// (was 800k global atomics-with-return). (2) spmm1+gemm2 fused — agg tile
// built in LDS, W2 GEMM applied in-block; agg1 (102MB round-trip) deleted.
// gemm1 kept from R8 (three restructures all land ~60us; parked).

#define F_IN  256
#define F_HID 128
#define F_CLS 40

#define RSZ 8192    // nodes per histogram range (32KB LDS)
#define NSL 32      // edge slices

typedef __bf16 bf16_t;
typedef bf16_t bf16x8 __attribute__((ext_vector_type(8)));
typedef float floatx4 __attribute__((ext_vector_type(4)));

static __device__ __forceinline__ unsigned short f2b(float f) {
    __hip_bfloat16 h = __float2bfloat16(f);   // RNE
    return __builtin_bit_cast(unsigned short, h);
}
static __device__ __forceinline__ float b2f(unsigned short u) {
    return __uint_as_float((unsigned)u << 16);
}

// ---- histogram partials: block (r, sl, y) counts keys-in-range from slice --
__global__ __launch_bounds__(256) void hist_kernel(
    const int* __restrict__ src, const int* __restrict__ dst,
    unsigned* __restrict__ partial_s, unsigned* __restrict__ partial_d, int E)
{
    __shared__ unsigned h[RSZ];
    const int t = threadIdx.x;
    const int r  = blockIdx.x / NSL;
    const int sl = blockIdx.x % NSL;
    const int lo = r * RSZ;
    const int* __restrict__ keys = blockIdx.y ? dst : src;
    unsigned* __restrict__ part = blockIdx.y ? partial_d : partial_s;

    for (int i = t; i < RSZ; i += 256) h[i] = 0;
    __syncthreads();

    const int slice = (E + NSL - 1) / NSL;
    const int e0 = sl * slice;
    const int e1 = min(E, e0 + slice);

    int e = e0 + t;
    for (; e + 7 * 256 < e1; e += 8 * 256) {
        int k[8];
        #pragma unroll
        for (int i = 0; i < 8; ++i) k[i] = keys[e + i * 256];
        #pragma unroll
        for (int i = 0; i < 8; ++i) {
            unsigned kk = (unsigned)(k[i] - lo);
            if (kk < RSZ) atomicAdd(&h[kk], 1u);
        }
    }
    for (; e < e1; e += 256) {
        unsigned kk = (unsigned)(keys[e] - lo);
        if (kk < RSZ) atomicAdd(&h[kk], 1u);
    }
    __syncthreads();

    unsigned* dst_p = part + (size_t)blockIdx.x * RSZ;
    for (int i = t; i < RSZ; i += 256) dst_p[i] = h[i];
}

// ---- reduce partials -> cnt_dst + norms ------------------------------------
__global__ __launch_bounds__(256) void degnorm_kernel(
    const unsigned* __restrict__ partial_s, const unsigned* __restrict__ partial_d,
    int* __restrict__ cnt_dst, float* __restrict__ norm_src,
    float* __restrict__ norm_dst, int N)
{
    int i = blockIdx.x * 256 + threadIdx.x;
    if (i >= N) return;
    int r = i / RSZ;
    int off = i & (RSZ - 1);
    const unsigned* ps = partial_s + (size_t)r * NSL * RSZ + off;
    const unsigned* pd = partial_d + (size_t)r * NSL * RSZ + off;
    unsigned ss = 0, sd = 0;
    #pragma unroll
    for (int sl = 0; sl < NSL; ++sl) {
        ss += ps[(size_t)sl * RSZ];
        sd += pd[(size_t)sl * RSZ];
    }
    cnt_dst[i] = (int)sd;
    norm_src[i] = ss ? 1.0f / sqrtf((float)ss) : 0.0f;
    norm_dst[i] = sd ? 1.0f / sqrtf((float)sd) : 0.0f;
}

// ---- hierarchical exclusive scan over cnt_dst (1024 elems / block) ---------
__global__ __launch_bounds__(256) void scan1_kernel(const int* __restrict__ cnt,
                                                    int* __restrict__ row_off,
                                                    int* __restrict__ blk_sums, int N) {
    __shared__ int s[256];
    const int t = threadIdx.x;
    const int base = blockIdx.x * 1024 + t * 4;
    int v0 = (base + 0 < N) ? cnt[base + 0] : 0;
    int v1 = (base + 1 < N) ? cnt[base + 1] : 0;
    int v2 = (base + 2 < N) ? cnt[base + 2] : 0;
    int v3 = (base + 3 < N) ? cnt[base + 3] : 0;
    int local = v0 + v1 + v2 + v3;
    s[t] = local;
    __syncthreads();
    for (int off = 1; off < 256; off <<= 1) {
        int x = (t >= off) ? s[t - off] : 0;
        __syncthreads();
        s[t] += x;
        __syncthreads();
    }
    int excl = s[t] - local;
    if (t == 255) blk_sums[blockIdx.x] = s[t];
    if (base + 0 < N) row_off[base + 0] = excl;
    if (base + 1 < N) row_off[base + 1] = excl + v0;
    if (base + 2 < N) row_off[base + 2] = excl + v0 + v1;
    if (base + 3 < N) row_off[base + 3] = excl + v0 + v1 + v2;
}

__global__ __launch_bounds__(256) void scan2_kernel(int* __restrict__ blk_sums, int B) {
    __shared__ int s[256];
    const int t = threadIdx.x;
    int local = (t < B) ? blk_sums[t] : 0;
    s[t] = local;
    __syncthreads();
    for (int off = 1; off < 256; off <<= 1) {
        int x = (t >= off) ? s[t - off] : 0;
        __syncthreads();
        s[t] += x;
        __syncthreads();
    }
    if (t < B) blk_sums[t] = s[t] - local;   // exclusive
}

__global__ __launch_bounds__(256) void scan3_kernel(int* __restrict__ row_off,
                                                    const int* __restrict__ blk_sums,
                                                    int N, int E) {
    const int t = threadIdx.x;
    const int base = blockIdx.x * 1024 + t * 4;
    const int add = blk_sums[blockIdx.x];
    #pragma unroll
    for (int i = 0; i < 4; ++i) {
        int idx = base + i;
        if (idx < N) row_off[idx] += add;
    }
    if (blockIdx.x == 0 && t == 0) row_off[N] = E;
}

// ---- in-place exclusive scan over slices: partial_d[r][sl][i] becomes the
// absolute csr start cursor for (range r, slice sl, node i) ------------------
__global__ __launch_bounds__(256) void slicepref_kernel(
    unsigned* __restrict__ partial_d, const int* __restrict__ row_off,
    int N, int NRtot)
{
    int idx = blockIdx.x * 256 + threadIdx.x;   // = r*RSZ + i = node id
    if (idx >= NRtot) return;
    int r = idx / RSZ;
    int i = idx & (RSZ - 1);
    unsigned run = (idx < N) ? (unsigned)row_off[idx] : 0u;
    unsigned* p = partial_d + (size_t)r * NSL * RSZ + i;
    #pragma unroll
    for (int sl = 0; sl < NSL; ++sl) {
        unsigned c = p[(size_t)sl * RSZ];
        p[(size_t)sl * RSZ] = run;
        run += c;
    }
}

// ---- scatter edges into CSR via LDS cursors (no global atomics) ------------
__global__ __launch_bounds__(256) void scatter2_kernel(
    const int* __restrict__ src, const int* __restrict__ dst,
    const unsigned* __restrict__ pref, int* __restrict__ csr_src, int E)
{
    __shared__ unsigned cur[RSZ];
    const int t = threadIdx.x;
    const int r  = blockIdx.x / NSL;
    const int sl = blockIdx.x % NSL;
    const int lo = r * RSZ;
    const unsigned* p = pref + (size_t)blockIdx.x * RSZ;   // [r][sl][.]

    for (int i = t; i < RSZ; i += 256) cur[i] = p[i];
    __syncthreads();

    const int slice = (E + NSL - 1) / NSL;
    const int e0 = sl * slice;
    const int e1 = min(E, e0 + slice);

    int e = e0 + t;
    for (; e + 7 * 256 < e1; e += 8 * 256) {
        int d[8], s[8];
        #pragma unroll
        for (int i = 0; i < 8; ++i) { d[i] = dst[e + i * 256]; s[i] = src[e + i * 256]; }
        #pragma unroll
        for (int i = 0; i < 8; ++i) {
            unsigned k = (unsigned)(d[i] - lo);
            if (k < RSZ) {
                unsigned pos = atomicAdd(&cur[k], 1u);
                csr_src[pos] = s[i];
            }
        }
    }
    for (; e < e1; e += 256) {
        unsigned k = (unsigned)(dst[e] - lo);
        if (k < RSZ) {
            unsigned pos = atomicAdd(&cur[k], 1u);
            csr_src[pos] = src[e];
        }
    }
}

// ---- pack W1 [256][128] fp32 -> W1t [128][256] bf16 (n-major, k contig) ----
__global__ __launch_bounds__(256) void pack_w1t_kernel(const float* __restrict__ W1,
                                                       __hip_bfloat16* __restrict__ W1t) {
    int idx = blockIdx.x * 256 + threadIdx.x;     // 32768 total
    int n = idx >> 8;
    int k = idx & 255;
    W1t[idx] = __float2bfloat16(W1[(size_t)k * F_HID + n]);
}

// ---- GEMM1 (MFMA): h1b[N,128] = bf16( (X*norm_src)bf16 @ W1bf16 ) ----------
// R8 structure: BK=64 chunks, A per-chunk in regs, B double-buffered LDS.
__global__ __launch_bounds__(256, 4) void gemm1_mfma_kernel(
    const float* __restrict__ X, const __hip_bfloat16* __restrict__ W1t,
    const float* __restrict__ norm_src, __hip_bfloat16* __restrict__ h1b, int N)
{
    __shared__ __hip_bfloat16 Bs[2][128][72];
    const int t = threadIdx.x;
    const int node0 = blockIdx.x * 64;
    const int lane = t & 63;
    const int w = t >> 6;
    const int l15 = lane & 15;
    const int quad = lane >> 4;

    const int arow = node0 + w * 16 + l15;
    const bool valid = arow < N;
    const int arow_c = valid ? arow : (N - 1);
    const float ns = valid ? norm_src[arow] : 0.0f;

    const int bn = t >> 1;
    const int bh = t & 1;
    const __hip_bfloat16* wp = W1t + (size_t)bn * F_IN + bh * 32;
    const float* xp = X + (size_t)arow_c * F_IN + quad * 8;

    uint4  breg[4];
    float4 araw[4];

    #pragma unroll
    for (int i = 0; i < 4; ++i) breg[i] = *(const uint4*)(wp + i * 8);
    araw[0] = *(const float4*)(xp + 0);
    araw[1] = *(const float4*)(xp + 4);
    araw[2] = *(const float4*)(xp + 32);
    araw[3] = *(const float4*)(xp + 36);

    floatx4 acc[8] = {};

    #pragma unroll
    for (int c = 0; c < 4; ++c) {
        #pragma unroll
        for (int j = 0; j < 4; ++j)
            *(uint4*)&Bs[c & 1][bn][bh * 32 + j * 8] = breg[j];
        __syncthreads();
        bf16x8 ab0, ab1;
        {
            union { bf16x8 v; unsigned short u[8]; } cv;
            cv.u[0] = f2b(araw[0].x * ns); cv.u[1] = f2b(araw[0].y * ns);
            cv.u[2] = f2b(araw[0].z * ns); cv.u[3] = f2b(araw[0].w * ns);
            cv.u[4] = f2b(araw[1].x * ns); cv.u[5] = f2b(araw[1].y * ns);
            cv.u[6] = f2b(araw[1].z * ns); cv.u[7] = f2b(araw[1].w * ns);
            ab0 = cv.v;
            cv.u[0] = f2b(araw[2].x * ns); cv.u[1] = f2b(araw[2].y * ns);
            cv.u[2] = f2b(araw[2].z * ns); cv.u[3] = f2b(araw[2].w * ns);
            cv.u[4] = f2b(araw[3].x * ns); cv.u[5] = f2b(araw[3].y * ns);
            cv.u[6] = f2b(araw[3].z * ns); cv.u[7] = f2b(araw[3].w * ns);
            ab1 = cv.v;
        }
        if (c < 3) {
            #pragma unroll
            for (int i = 0; i < 4; ++i)
                breg[i] = *(const uint4*)(wp + (c + 1) * 64 + i * 8);
            araw[0] = *(const float4*)(xp + (c + 1) * 64 + 0);
            araw[1] = *(const float4*)(xp + (c + 1) * 64 + 4);
            araw[2] = *(const float4*)(xp + (c + 1) * 64 + 32);
            araw[3] = *(const float4*)(xp + (c + 1) * 64 + 36);
        }
        #pragma unroll
        for (int nt = 0; nt < 8; ++nt) {
            bf16x8 b = *(const bf16x8*)&Bs[c & 1][nt * 16 + l15][quad * 8];
            acc[nt] = __builtin_amdgcn_mfma_f32_16x16x32_bf16(ab0, b, acc[nt], 0, 0, 0);
        }
        #pragma unroll
        for (int nt = 0; nt < 8; ++nt) {
            bf16x8 b = *(const bf16x8*)&Bs[c & 1][nt * 16 + l15][32 + quad * 8];
            acc[nt] = __builtin_amdgcn_mfma_f32_16x16x32_bf16(ab1, b, acc[nt], 0, 0, 0);
        }
    }

    #pragma unroll
    for (int nt = 0; nt < 8; ++nt) {
        #pragma unroll
        for (int r = 0; r < 4; ++r) {
            int node = node0 + w * 16 + quad * 4 + r;
            if (node < N)
                h1b[(size_t)node * F_HID + nt * 16 + l15] = __float2bfloat16(acc[nt][r]);
        }
    }
}

// ---- FUSED SpMM1 + GEMM2: h2 = relu((sum h1b[src])*nd + b1)*ns @ W2 --------
// 320 thr. Agg: 20 groups of 16 lanes, 8 cols (16B bf16) per lane per node,
// agg tile -> LDS As[64][132] with epilogue fused. Then VALU GEMM over W2.
__global__ __launch_bounds__(320) void spmm_gemm2_kernel(
    const __hip_bfloat16* __restrict__ h1b, const int* __restrict__ row_off,
    const int* __restrict__ csr_src, const float* __restrict__ W2,
    const float* __restrict__ b1, const float* __restrict__ norm_src,
    const float* __restrict__ norm_dst, float* __restrict__ h2, int N)
{
    __shared__ float As[64][132];
    __shared__ float Ws[128][40];
    const int t = threadIdx.x;
    const int node0 = blockIdx.x * 64;

    // W2 -> LDS: 1280 float4s, 4 per thread
    #pragma unroll
    for (int i = 0; i < 4; ++i) {
        int f = t + 320 * i;
        int r = f / 10;
        int kk = (f % 10) * 4;
        *(float4*)&Ws[r][kk] = *(const float4*)(W2 + (size_t)r * F_CLS + kk);
    }

    // aggregate + epilogue into As
    const int g = t >> 4;          // 0..19
    const int cc = (t & 15) << 3;  // col start (8 cols, 16B bf16)
    for (int n = g; n < 64; n += 20) {
        int node = node0 + n;
        float4 a0 = make_float4(0.f, 0.f, 0.f, 0.f);
        float4 a1 = make_float4(0.f, 0.f, 0.f, 0.f);
        if (node < N) {
            const int start = row_off[node];
            const int end = row_off[node + 1];
            int j = start;
            for (; j + 4 <= end; j += 4) {
                int s0 = csr_src[j + 0];
                int s1 = csr_src[j + 1];
                int s2 = csr_src[j + 2];
                int s3 = csr_src[j + 3];
                union { uint4 v; unsigned short u[8]; } q0, q1, q2, q3;
                q0.v = *(const uint4*)(h1b + (size_t)s0 * F_HID + cc);
                q1.v = *(const uint4*)(h1b + (size_t)s1 * F_HID + cc);
                q2.v = *(const uint4*)(h1b + (size_t)s2 * F_HID + cc);
                q3.v = *(const uint4*)(h1b + (size_t)s3 * F_HID + cc);
                a0.x += b2f(q0.u[0]) + b2f(q1.u[0]) + b2f(q2.u[0]) + b2f(q3.u[0]);
                a0.y += b2f(q0.u[1]) + b2f(q1.u[1]) + b2f(q2.u[1]) + b2f(q3.u[1]);
                a0.z += b2f(q0.u[2]) + b2f(q1.u[2]) + b2f(q2.u[2]) + b2f(q3.u[2]);
                a0.w += b2f(q0.u[3]) + b2f(q1.u[3]) + b2f(q2.u[3]) + b2f(q3.u[3]);
                a1.x += b2f(q0.u[4]) + b2f(q1.u[4]) + b2f(q2.u[4]) + b2f(q3.u[4]);
                a1.y += b2f(q0.u[5]) + b2f(q1.u[5]) + b2f(q2.u[5]) + b2f(q3.u[5]);
                a1.z += b2f(q0.u[6]) + b2f(q1.u[6]) + b2f(q2.u[6]) + b2f(q3.u[6]);
                a1.w += b2f(q0.u[7]) + b2f(q1.u[7]) + b2f(q2.u[7]) + b2f(q3.u[7]);
            }
            for (; j < end; ++j) {
                int s = csr_src[j];
                union { uint4 v; unsigned short u[8]; } q;
                q.v = *(const uint4*)(h1b + (size_t)s * F_HID + cc);
                a0.x += b2f(q.u[0]); a0.y += b2f(q.u[1]);
                a0.z += b2f(q.u[2]); a0.w += b2f(q.u[3]);
                a1.x += b2f(q.u[4]); a1.y += b2f(q.u[5]);
                a1.z += b2f(q.u[6]); a1.w += b2f(q.u[7]);
            }
            float nd = norm_dst[node];
            float ns2 = norm_src[node];
            float4 bb0 = *(const float4*)(b1 + cc);
            float4 bb1 = *(const float4*)(b1 + cc + 4);
            a0.x = fmaxf(fmaf(a0.x, nd, bb0.x), 0.f) * ns2;
            a0.y = fmaxf(fmaf(a0.y, nd, bb0.y), 0.f) * ns2;
            a0.z = fmaxf(fmaf(a0.z, nd, bb0.z), 0.f) * ns2;
            a0.w = fmaxf(fmaf(a0.w, nd, bb0.w), 0.f) * ns2;
            a1.x = fmaxf(fmaf(a1.x, nd, bb1.x), 0.f) * ns2;
            a1.y = fmaxf(fmaf(a1.y, nd, bb1.y), 0.f) * ns2;
            a1.z = fmaxf(fmaf(a1.z, nd, bb1.z), 0.f) * ns2;
            a1.w = fmaxf(fmaf(a1.w, nd, bb1.w), 0.f) * ns2;
        }
        *(float4*)&As[n][cc] = a0;
        *(float4*)&As[n][cc + 4] = a1;
    }
    __syncthreads();

    // GEMM over W2 (unchanged from R8 gemm2)
    const int col = t % 40;
    const int rowg = t / 40;
    float acc[8] = {};
    #pragma unroll 8
    for (int k = 0; k < F_HID; ++k) {
        float w = Ws[k][col];
        #pragma unroll
        for (int i = 0; i < 8; ++i)
            acc[i] = fmaf(As[rowg * 8 + i][k], w, acc[i]);
    }
    #pragma unroll
    for (int i = 0; i < 8; ++i) {
        int node = node0 + rowg * 8 + i;
        if (node < N) h2[(size_t)node * F_CLS + col] = acc[i];
    }
}

// ---- SpMM2 (CSR) + epilogue: out[n,:] = (sum h2[src,:])*norm_dst[n] + b2 ---
__global__ __launch_bounds__(256) void spmm2_csr_kernel(
    const float* __restrict__ h2, const int* __restrict__ row_off,
    const int* __restrict__ csr_src, const float* __restrict__ norm_dst,
    const float* __restrict__ b2, float* __restrict__ out, int N)
{
    const int t = threadIdx.x;
    const int node = blockIdx.x * 16 + (t >> 4);
    const int lane = t & 15;
    if (node >= N || lane >= 10) return;
    const int c = lane << 2;
    const int start = row_off[node];
    const int end = row_off[node + 1];
    float4 acc = make_float4(0.f, 0.f, 0.f, 0.f);
    int j = start;
    for (; j + 4 <= end; j += 4) {
        int s0 = csr_src[j + 0];
        int s1 = csr_src[j + 1];
        int s2 = csr_src[j + 2];
        int s3 = csr_src[j + 3];
        float4 v0 = *(const float4*)(h2 + (size_t)s0 * F_CLS + c);
        float4 v1 = *(const float4*)(h2 + (size_t)s1 * F_CLS + c);
        float4 v2 = *(const float4*)(h2 + (size_t)s2 * F_CLS + c);
        float4 v3 = *(const float4*)(h2 + (size_t)s3 * F_CLS + c);
        acc.x += v0.x + v1.x + v2.x + v3.x;
        acc.y += v0.y + v1.y + v2.y + v3.y;
        acc.z += v0.z + v1.z + v2.z + v3.z;
        acc.w += v0.w + v1.w + v2.w + v3.w;
    }
    for (; j < end; ++j) {
        int s = csr_src[j];
        float4 v = *(const float4*)(h2 + (size_t)s * F_CLS + c);
        acc.x += v.x; acc.y += v.y; acc.z += v.z; acc.w += v.w;
    }
    float nd = norm_dst[node];
    float4 bb = *(const float4*)(b2 + c);
    float4 r;
    r.x = fmaf(acc.x, nd, bb.x);
    r.y = fmaf(acc.y, nd, bb.y);
    r.z = fmaf(acc.z, nd, bb.z);
    r.w = fmaf(acc.w, nd, bb.w);
    *(float4*)(out + (size_t)node * F_CLS + c) = r;
}

extern "C" void kernel_launch(void* const* d_in, const int* in_sizes, int n_in,
                              void* d_out, int out_size, void* d_ws, size_t ws_size,
                              hipStream_t stream) {
    const float* X   = (const float*)d_in[0];
    const int*   src = (const int*)d_in[1];
    const int*   dst = (const int*)d_in[2];
    const float* W1  = (const float*)d_in[3];
    const float* b1  = (const float*)d_in[4];
    const float* W2  = (const float*)d_in[5];
    const float* b2  = (const float*)d_in[6];
    float* out = (float*)d_out;

    const int N = in_sizes[0] / F_IN;
    const int E = in_sizes[1];
    const int NB = (N + 1023) / 1024;     // scan blocks (<= 256)
    const int NR = (N + RSZ - 1) / RSZ;   // histogram ranges
    const int NRtot = NR * RSZ;

    // workspace layout — keep every array 16B-aligned
    char* w = (char*)d_ws;
    int*   cnt_dst  = (int*)w;                      w += (size_t)N * 4;
    int*   row_off  = (int*)w;                      w += (size_t)(N + 4) * 4;
    int*   blk_sums = (int*)w;                      w += 256 * 4;
    int*   csr_src  = (int*)w;                      w += (size_t)E * 4;
    float* norm_src = (float*)w;                    w += (size_t)N * 4;
    float* norm_dst = (float*)w;                    w += (size_t)N * 4;
    float* h2       = (float*)w;                    w += (size_t)N * F_CLS * 4;
    __hip_bfloat16* W1t = (__hip_bfloat16*)w;       w += (size_t)F_HID * F_IN * 2;
    __hip_bfloat16* h1b = (__hip_bfloat16*)w;       w += (size_t)N * F_HID * 2;
    unsigned* partial_s = (unsigned*)w;             w += (size_t)NR * NSL * RSZ * 4;
    unsigned* partial_d = (unsigned*)w;             w += (size_t)NR * NSL * RSZ * 4;

    hist_kernel<<<dim3(NR * NSL, 2), 256, 0, stream>>>(src, dst, partial_s, partial_d, E);
    degnorm_kernel<<<(N + 255) / 256, 256, 0, stream>>>(partial_s, partial_d,
                                                        cnt_dst, norm_src, norm_dst, N);

    scan1_kernel<<<NB, 256, 0, stream>>>(cnt_dst, row_off, blk_sums, N);
    scan2_kernel<<<1, 256, 0, stream>>>(blk_sums, NB);
    scan3_kernel<<<NB, 256, 0, stream>>>(row_off, blk_sums, N, E);

    slicepref_kernel<<<(NRtot + 255) / 256, 256, 0, stream>>>(partial_d, row_off, N, NRtot);
    scatter2_kernel<<<NR * NSL, 256, 0, stream>>>(src, dst, partial_d, csr_src, E);

    pack_w1t_kernel<<<(F_HID * F_IN) / 256, 256, 0, stream>>>(W1, W1t);

    gemm1_mfma_kernel<<<(N + 63) / 64, 256, 0, stream>>>(X, W1t, norm_src, h1b, N);

    spmm_gemm2_kernel<<<(N + 63) / 64, 320, 0, stream>>>(h1b, row_off, csr_src, W2,
                                                         b1, norm_src, norm_dst, h2, N);

    spmm2_csr_kernel<<<(N + 15) / 16, 256, 0, stream>>>(h2, row_off, csr_src, norm_dst, b2, out, N);
}

// Round 10
// 364.368 us; speedup vs baseline: 1.1210x; 1.0251x over previous
//
#include <hip/hip_runtime.h>
#include <hip/hip_bf16.h>
#include <math.h>

// GCN 2-layer: h = Ddst^-1/2 A (Dsrc^-1/2 x) W + b, relu between.
// R10: UN-fuse spmm1+gemm2 (R9 fusion = 100us at 20% occupancy; the random
// gather is latency-bound and needs the separate kernel's high occupancy).
// spmm1/spmm2 get 8-deep gather batching for MLP. Atomic-free scatter (R9)
// and bf16-MFMA gemm1 (R8) retained. Note: 2x400MB harness poison fills
// (~122us) sit inside the timed window — fixed cost.

#define F_IN  256
#define F_HID 128
#define F_CLS 40

#define RSZ 8192    // nodes per histogram range (32KB LDS)
#define NSL 32      // edge slices

typedef __bf16 bf16_t;
typedef bf16_t bf16x8 __attribute__((ext_vector_type(8)));
typedef float floatx4 __attribute__((ext_vector_type(4)));

static __device__ __forceinline__ unsigned short f2b(float f) {
    __hip_bfloat16 h = __float2bfloat16(f);   // RNE
    return __builtin_bit_cast(unsigned short, h);
}
static __device__ __forceinline__ float b2f(unsigned short u) {
    return __uint_as_float((unsigned)u << 16);
}

// ---- histogram partials: block (r, sl, y) counts keys-in-range from slice --
__global__ __launch_bounds__(256) void hist_kernel(
    const int* __restrict__ src, const int* __restrict__ dst,
    unsigned* __restrict__ partial_s, unsigned* __restrict__ partial_d, int E)
{
    __shared__ unsigned h[RSZ];
    const int t = threadIdx.x;
    const int r  = blockIdx.x / NSL;
    const int sl = blockIdx.x % NSL;
    const int lo = r * RSZ;
    const int* __restrict__ keys = blockIdx.y ? dst : src;
    unsigned* __restrict__ part = blockIdx.y ? partial_d : partial_s;

    for (int i = t; i < RSZ; i += 256) h[i] = 0;
    __syncthreads();

    const int slice = (E + NSL - 1) / NSL;
    const int e0 = sl * slice;
    const int e1 = min(E, e0 + slice);

    int e = e0 + t;
    for (; e + 7 * 256 < e1; e += 8 * 256) {
        int k[8];
        #pragma unroll
        for (int i = 0; i < 8; ++i) k[i] = keys[e + i * 256];
        #pragma unroll
        for (int i = 0; i < 8; ++i) {
            unsigned kk = (unsigned)(k[i] - lo);
            if (kk < RSZ) atomicAdd(&h[kk], 1u);
        }
    }
    for (; e < e1; e += 256) {
        unsigned kk = (unsigned)(keys[e] - lo);
        if (kk < RSZ) atomicAdd(&h[kk], 1u);
    }
    __syncthreads();

    unsigned* dst_p = part + (size_t)blockIdx.x * RSZ;
    for (int i = t; i < RSZ; i += 256) dst_p[i] = h[i];
}

// ---- reduce partials -> cnt_dst + norms ------------------------------------
__global__ __launch_bounds__(256) void degnorm_kernel(
    const unsigned* __restrict__ partial_s, const unsigned* __restrict__ partial_d,
    int* __restrict__ cnt_dst, float* __restrict__ norm_src,
    float* __restrict__ norm_dst, int N)
{
    int i = blockIdx.x * 256 + threadIdx.x;
    if (i >= N) return;
    int r = i / RSZ;
    int off = i & (RSZ - 1);
    const unsigned* ps = partial_s + (size_t)r * NSL * RSZ + off;
    const unsigned* pd = partial_d + (size_t)r * NSL * RSZ + off;
    unsigned ss = 0, sd = 0;
    #pragma unroll
    for (int sl = 0; sl < NSL; ++sl) {
        ss += ps[(size_t)sl * RSZ];
        sd += pd[(size_t)sl * RSZ];
    }
    cnt_dst[i] = (int)sd;
    norm_src[i] = ss ? 1.0f / sqrtf((float)ss) : 0.0f;
    norm_dst[i] = sd ? 1.0f / sqrtf((float)sd) : 0.0f;
}

// ---- hierarchical exclusive scan over cnt_dst (1024 elems / block) ---------
__global__ __launch_bounds__(256) void scan1_kernel(const int* __restrict__ cnt,
                                                    int* __restrict__ row_off,
                                                    int* __restrict__ blk_sums, int N) {
    __shared__ int s[256];
    const int t = threadIdx.x;
    const int base = blockIdx.x * 1024 + t * 4;
    int v0 = (base + 0 < N) ? cnt[base + 0] : 0;
    int v1 = (base + 1 < N) ? cnt[base + 1] : 0;
    int v2 = (base + 2 < N) ? cnt[base + 2] : 0;
    int v3 = (base + 3 < N) ? cnt[base + 3] : 0;
    int local = v0 + v1 + v2 + v3;
    s[t] = local;
    __syncthreads();
    for (int off = 1; off < 256; off <<= 1) {
        int x = (t >= off) ? s[t - off] : 0;
        __syncthreads();
        s[t] += x;
        __syncthreads();
    }
    int excl = s[t] - local;
    if (t == 255) blk_sums[blockIdx.x] = s[t];
    if (base + 0 < N) row_off[base + 0] = excl;
    if (base + 1 < N) row_off[base + 1] = excl + v0;
    if (base + 2 < N) row_off[base + 2] = excl + v0 + v1;
    if (base + 3 < N) row_off[base + 3] = excl + v0 + v1 + v2;
}

__global__ __launch_bounds__(256) void scan2_kernel(int* __restrict__ blk_sums, int B) {
    __shared__ int s[256];
    const int t = threadIdx.x;
    int local = (t < B) ? blk_sums[t] : 0;
    s[t] = local;
    __syncthreads();
    for (int off = 1; off < 256; off <<= 1) {
        int x = (t >= off) ? s[t - off] : 0;
        __syncthreads();
        s[t] += x;
        __syncthreads();
    }
    if (t < B) blk_sums[t] = s[t] - local;   // exclusive
}

__global__ __launch_bounds__(256) void scan3_kernel(int* __restrict__ row_off,
                                                    const int* __restrict__ blk_sums,
                                                    int N, int E) {
    const int t = threadIdx.x;
    const int base = blockIdx.x * 1024 + t * 4;
    const int add = blk_sums[blockIdx.x];
    #pragma unroll
    for (int i = 0; i < 4; ++i) {
        int idx = base + i;
        if (idx < N) row_off[idx] += add;
    }
    if (blockIdx.x == 0 && t == 0) row_off[N] = E;
}

// ---- in-place exclusive scan over slices -> absolute csr cursors -----------
__global__ __launch_bounds__(256) void slicepref_kernel(
    unsigned* __restrict__ partial_d, const int* __restrict__ row_off,
    int N, int NRtot)
{
    int idx = blockIdx.x * 256 + threadIdx.x;   // = r*RSZ + i = node id
    if (idx >= NRtot) return;
    int r = idx / RSZ;
    int i = idx & (RSZ - 1);
    unsigned run = (idx < N) ? (unsigned)row_off[idx] : 0u;
    unsigned* p = partial_d + (size_t)r * NSL * RSZ + i;
    #pragma unroll
    for (int sl = 0; sl < NSL; ++sl) {
        unsigned c = p[(size_t)sl * RSZ];
        p[(size_t)sl * RSZ] = run;
        run += c;
    }
}

// ---- scatter edges into CSR via LDS cursors (no global atomics) ------------
__global__ __launch_bounds__(256) void scatter2_kernel(
    const int* __restrict__ src, const int* __restrict__ dst,
    const unsigned* __restrict__ pref, int* __restrict__ csr_src, int E)
{
    __shared__ unsigned cur[RSZ];
    const int t = threadIdx.x;
    const int r  = blockIdx.x / NSL;
    const int sl = blockIdx.x % NSL;
    const int lo = r * RSZ;
    const unsigned* p = pref + (size_t)blockIdx.x * RSZ;   // [r][sl][.]

    for (int i = t; i < RSZ; i += 256) cur[i] = p[i];
    __syncthreads();

    const int slice = (E + NSL - 1) / NSL;
    const int e0 = sl * slice;
    const int e1 = min(E, e0 + slice);

    int e = e0 + t;
    for (; e + 7 * 256 < e1; e += 8 * 256) {
        int d[8], s[8];
        #pragma unroll
        for (int i = 0; i < 8; ++i) { d[i] = dst[e + i * 256]; s[i] = src[e + i * 256]; }
        #pragma unroll
        for (int i = 0; i < 8; ++i) {
            unsigned k = (unsigned)(d[i] - lo);
            if (k < RSZ) {
                unsigned pos = atomicAdd(&cur[k], 1u);
                csr_src[pos] = s[i];
            }
        }
    }
    for (; e < e1; e += 256) {
        unsigned k = (unsigned)(dst[e] - lo);
        if (k < RSZ) {
            unsigned pos = atomicAdd(&cur[k], 1u);
            csr_src[pos] = src[e];
        }
    }
}

// ---- pack W1 [256][128] fp32 -> W1t [128][256] bf16 (n-major, k contig) ----
__global__ __launch_bounds__(256) void pack_w1t_kernel(const float* __restrict__ W1,
                                                       __hip_bfloat16* __restrict__ W1t) {
    int idx = blockIdx.x * 256 + threadIdx.x;     // 32768 total
    int n = idx >> 8;
    int k = idx & 255;
    W1t[idx] = __float2bfloat16(W1[(size_t)k * F_HID + n]);
}

// ---- GEMM1 (MFMA): h1b[N,128] = bf16( (X*norm_src)bf16 @ W1bf16 ) ----------
// R8 structure: BK=64 chunks, A per-chunk in regs, B double-buffered LDS.
__global__ __launch_bounds__(256, 4) void gemm1_mfma_kernel(
    const float* __restrict__ X, const __hip_bfloat16* __restrict__ W1t,
    const float* __restrict__ norm_src, __hip_bfloat16* __restrict__ h1b, int N)
{
    __shared__ __hip_bfloat16 Bs[2][128][72];
    const int t = threadIdx.x;
    const int node0 = blockIdx.x * 64;
    const int lane = t & 63;
    const int w = t >> 6;
    const int l15 = lane & 15;
    const int quad = lane >> 4;

    const int arow = node0 + w * 16 + l15;
    const bool valid = arow < N;
    const int arow_c = valid ? arow : (N - 1);
    const float ns = valid ? norm_src[arow] : 0.0f;

    const int bn = t >> 1;
    const int bh = t & 1;
    const __hip_bfloat16* wp = W1t + (size_t)bn * F_IN + bh * 32;
    const float* xp = X + (size_t)arow_c * F_IN + quad * 8;

    uint4  breg[4];
    float4 araw[4];

    #pragma unroll
    for (int i = 0; i < 4; ++i) breg[i] = *(const uint4*)(wp + i * 8);
    araw[0] = *(const float4*)(xp + 0);
    araw[1] = *(const float4*)(xp + 4);
    araw[2] = *(const float4*)(xp + 32);
    araw[3] = *(const float4*)(xp + 36);

    floatx4 acc[8] = {};

    #pragma unroll
    for (int c = 0; c < 4; ++c) {
        #pragma unroll
        for (int j = 0; j < 4; ++j)
            *(uint4*)&Bs[c & 1][bn][bh * 32 + j * 8] = breg[j];
        __syncthreads();
        bf16x8 ab0, ab1;
        {
            union { bf16x8 v; unsigned short u[8]; } cv;
            cv.u[0] = f2b(araw[0].x * ns); cv.u[1] = f2b(araw[0].y * ns);
            cv.u[2] = f2b(araw[0].z * ns); cv.u[3] = f2b(araw[0].w * ns);
            cv.u[4] = f2b(araw[1].x * ns); cv.u[5] = f2b(araw[1].y * ns);
            cv.u[6] = f2b(araw[1].z * ns); cv.u[7] = f2b(araw[1].w * ns);
            ab0 = cv.v;
            cv.u[0] = f2b(araw[2].x * ns); cv.u[1] = f2b(araw[2].y * ns);
            cv.u[2] = f2b(araw[2].z * ns); cv.u[3] = f2b(araw[2].w * ns);
            cv.u[4] = f2b(araw[3].x * ns); cv.u[5] = f2b(araw[3].y * ns);
            cv.u[6] = f2b(araw[3].z * ns); cv.u[7] = f2b(araw[3].w * ns);
            ab1 = cv.v;
        }
        if (c < 3) {
            #pragma unroll
            for (int i = 0; i < 4; ++i)
                breg[i] = *(const uint4*)(wp + (c + 1) * 64 + i * 8);
            araw[0] = *(const float4*)(xp + (c + 1) * 64 + 0);
            araw[1] = *(const float4*)(xp + (c + 1) * 64 + 4);
            araw[2] = *(const float4*)(xp + (c + 1) * 64 + 32);
            araw[3] = *(const float4*)(xp + (c + 1) * 64 + 36);
        }
        #pragma unroll
        for (int nt = 0; nt < 8; ++nt) {
            bf16x8 b = *(const bf16x8*)&Bs[c & 1][nt * 16 + l15][quad * 8];
            acc[nt] = __builtin_amdgcn_mfma_f32_16x16x32_bf16(ab0, b, acc[nt], 0, 0, 0);
        }
        #pragma unroll
        for (int nt = 0; nt < 8; ++nt) {
            bf16x8 b = *(const bf16x8*)&Bs[c & 1][nt * 16 + l15][32 + quad * 8];
            acc[nt] = __builtin_amdgcn_mfma_f32_16x16x32_bf16(ab1, b, acc[nt], 0, 0, 0);
        }
    }

    #pragma unroll
    for (int nt = 0; nt < 8; ++nt) {
        #pragma unroll
        for (int r = 0; r < 4; ++r) {
            int node = node0 + w * 16 + quad * 4 + r;
            if (node < N)
                h1b[(size_t)node * F_HID + nt * 16 + l15] = __float2bfloat16(acc[nt][r]);
        }
    }
}

// ---- SpMM1 (CSR, bf16 gather): agg1[n,:] = sum h1b[csr_src,:] --------------
// 8 nodes/block, 32 lanes/node; 8-deep gather batching for MLP.
__global__ __launch_bounds__(256) void spmm1_csr_kernel(
    const __hip_bfloat16* __restrict__ h1b, const int* __restrict__ row_off,
    const int* __restrict__ csr_src, float* __restrict__ agg1, int N)
{
    const int t = threadIdx.x;
    const int node = blockIdx.x * 8 + (t >> 5);
    if (node >= N) return;
    const int c = (t & 31) << 2;
    const int start = row_off[node];
    const int end = row_off[node + 1];
    float4 acc = make_float4(0.f, 0.f, 0.f, 0.f);
    int j = start;
    for (; j + 8 <= end; j += 8) {
        int s[8];
        #pragma unroll
        for (int i = 0; i < 8; ++i) s[i] = csr_src[j + i];
        ushort4 u[8];
        #pragma unroll
        for (int i = 0; i < 8; ++i)
            u[i] = *(const ushort4*)(h1b + (size_t)s[i] * F_HID + c);
        #pragma unroll
        for (int i = 0; i < 8; ++i) {
            acc.x += b2f(u[i].x);
            acc.y += b2f(u[i].y);
            acc.z += b2f(u[i].z);
            acc.w += b2f(u[i].w);
        }
    }
    for (; j + 2 <= end; j += 2) {
        int s0 = csr_src[j + 0];
        int s1 = csr_src[j + 1];
        ushort4 u0 = *(const ushort4*)(h1b + (size_t)s0 * F_HID + c);
        ushort4 u1 = *(const ushort4*)(h1b + (size_t)s1 * F_HID + c);
        acc.x += b2f(u0.x) + b2f(u1.x);
        acc.y += b2f(u0.y) + b2f(u1.y);
        acc.z += b2f(u0.z) + b2f(u1.z);
        acc.w += b2f(u0.w) + b2f(u1.w);
    }
    if (j < end) {
        int s = csr_src[j];
        ushort4 u = *(const ushort4*)(h1b + (size_t)s * F_HID + c);
        acc.x += b2f(u.x);
        acc.y += b2f(u.y);
        acc.z += b2f(u.z);
        acc.w += b2f(u.w);
    }
    *(float4*)(agg1 + (size_t)node * F_HID + c) = acc;
}

// ---- GEMM2: h2[N,40] = relu(agg1*norm_dst + b1)*norm_src @ W2[128,40] ------
__global__ __launch_bounds__(320) void gemm2_kernel(
    const float* __restrict__ agg1, const float* __restrict__ W2,
    const float* __restrict__ b1, const float* __restrict__ norm_src,
    const float* __restrict__ norm_dst, float* __restrict__ h2, int N)
{
    __shared__ float As[64][132];
    __shared__ float Ws[128][40];
    const int t = threadIdx.x;
    const int node0 = blockIdx.x * 64;

    #pragma unroll
    for (int i = 0; i < 4; ++i) {
        int f = t + 320 * i;
        int r = f / 10;
        int kk = (f % 10) * 4;
        *(float4*)&Ws[r][kk] = *(const float4*)(W2 + (size_t)r * F_CLS + kk);
    }
    for (int f = t; f < 2048; f += 320) {
        int r = f >> 5;
        int kk = (f & 31) << 2;
        int node = node0 + r;
        float4 v = make_float4(0.f, 0.f, 0.f, 0.f);
        if (node < N) {
            float4 a = *(const float4*)(agg1 + (size_t)node * F_HID + kk);
            float nd = norm_dst[node];
            float ns = norm_src[node];
            float4 bb = *(const float4*)(b1 + kk);
            v.x = fmaxf(fmaf(a.x, nd, bb.x), 0.f) * ns;
            v.y = fmaxf(fmaf(a.y, nd, bb.y), 0.f) * ns;
            v.z = fmaxf(fmaf(a.z, nd, bb.z), 0.f) * ns;
            v.w = fmaxf(fmaf(a.w, nd, bb.w), 0.f) * ns;
        }
        *(float4*)&As[r][kk] = v;
    }
    __syncthreads();

    const int col = t % 40;
    const int rowg = t / 40;
    float acc[8] = {};
    #pragma unroll 8
    for (int k = 0; k < F_HID; ++k) {
        float w = Ws[k][col];
        #pragma unroll
        for (int i = 0; i < 8; ++i)
            acc[i] = fmaf(As[rowg * 8 + i][k], w, acc[i]);
    }
    #pragma unroll
    for (int i = 0; i < 8; ++i) {
        int node = node0 + rowg * 8 + i;
        if (node < N) h2[(size_t)node * F_CLS + col] = acc[i];
    }
}

// ---- SpMM2 (CSR) + epilogue: out[n,:] = (sum h2[src,:])*norm_dst[n] + b2 ---
// 16 groups of 16 lanes (10 active), 8-deep gather batching.
__global__ __launch_bounds__(256) void spmm2_csr_kernel(
    const float* __restrict__ h2, const int* __restrict__ row_off,
    const int* __restrict__ csr_src, const float* __restrict__ norm_dst,
    const float* __restrict__ b2, float* __restrict__ out, int N)
{
    const int t = threadIdx.x;
    const int node = blockIdx.x * 16 + (t >> 4);
    const int lane = t & 15;
    if (node >= N || lane >= 10) return;
    const int c = lane << 2;
    const int start = row_off[node];
    const int end = row_off[node + 1];
    float4 acc = make_float4(0.f, 0.f, 0.f, 0.f);
    int j = start;
    for (; j + 8 <= end; j += 8) {
        int s[8];
        #pragma unroll
        for (int i = 0; i < 8; ++i) s[i] = csr_src[j + i];
        float4 v[8];
        #pragma unroll
        for (int i = 0; i < 8; ++i)
            v[i] = *(const float4*)(h2 + (size_t)s[i] * F_CLS + c);
        #pragma unroll
        for (int i = 0; i < 8; ++i) {
            acc.x += v[i].x; acc.y += v[i].y; acc.z += v[i].z; acc.w += v[i].w;
        }
    }
    for (; j + 2 <= end; j += 2) {
        int s0 = csr_src[j + 0];
        int s1 = csr_src[j + 1];
        float4 v0 = *(const float4*)(h2 + (size_t)s0 * F_CLS + c);
        float4 v1 = *(const float4*)(h2 + (size_t)s1 * F_CLS + c);
        acc.x += v0.x + v1.x;
        acc.y += v0.y + v1.y;
        acc.z += v0.z + v1.z;
        acc.w += v0.w + v1.w;
    }
    if (j < end) {
        int s = csr_src[j];
        float4 v = *(const float4*)(h2 + (size_t)s * F_CLS + c);
        acc.x += v.x; acc.y += v.y; acc.z += v.z; acc.w += v.w;
    }
    float nd = norm_dst[node];
    float4 bb = *(const float4*)(b2 + c);
    float4 r;
    r.x = fmaf(acc.x, nd, bb.x);
    r.y = fmaf(acc.y, nd, bb.y);
    r.z = fmaf(acc.z, nd, bb.z);
    r.w = fmaf(acc.w, nd, bb.w);
    *(float4*)(out + (size_t)node * F_CLS + c) = r;
}

extern "C" void kernel_launch(void* const* d_in, const int* in_sizes, int n_in,
                              void* d_out, int out_size, void* d_ws, size_t ws_size,
                              hipStream_t stream) {
    const float* X   = (const float*)d_in[0];
    const int*   src = (const int*)d_in[1];
    const int*   dst = (const int*)d_in[2];
    const float* W1  = (const float*)d_in[3];
    const float* b1  = (const float*)d_in[4];
    const float* W2  = (const float*)d_in[5];
    const float* b2  = (const float*)d_in[6];
    float* out = (float*)d_out;

    const int N = in_sizes[0] / F_IN;
    const int E = in_sizes[1];
    const int NB = (N + 1023) / 1024;     // scan blocks (<= 256)
    const int NR = (N + RSZ - 1) / RSZ;   // histogram ranges
    const int NRtot = NR * RSZ;

    // workspace layout — keep every array 16B-aligned
    char* w = (char*)d_ws;
    int*   cnt_dst  = (int*)w;                      w += (size_t)N * 4;
    int*   row_off  = (int*)w;                      w += (size_t)(N + 4) * 4;
    int*   blk_sums = (int*)w;                      w += 256 * 4;
    int*   csr_src  = (int*)w;                      w += (size_t)E * 4;
    float* norm_src = (float*)w;                    w += (size_t)N * 4;
    float* norm_dst = (float*)w;                    w += (size_t)N * 4;
    float* agg1     = (float*)w;                    w += (size_t)N * F_HID * 4;
    float* h2       = (float*)w;                    w += (size_t)N * F_CLS * 4;
    __hip_bfloat16* W1t = (__hip_bfloat16*)w;       w += (size_t)F_HID * F_IN * 2;
    __hip_bfloat16* h1b = (__hip_bfloat16*)w;       w += (size_t)N * F_HID * 2;
    unsigned* partial_s = (unsigned*)w;             w += (size_t)NR * NSL * RSZ * 4;
    unsigned* partial_d = (unsigned*)w;             w += (size_t)NR * NSL * RSZ * 4;

    hist_kernel<<<dim3(NR * NSL, 2), 256, 0, stream>>>(src, dst, partial_s, partial_d, E);
    degnorm_kernel<<<(N + 255) / 256, 256, 0, stream>>>(partial_s, partial_d,
                                                        cnt_dst, norm_src, norm_dst, N);

    scan1_kernel<<<NB, 256, 0, stream>>>(cnt_dst, row_off, blk_sums, N);
    scan2_kernel<<<1, 256, 0, stream>>>(blk_sums, NB);
    scan3_kernel<<<NB, 256, 0, stream>>>(row_off, blk_sums, N, E);

    slicepref_kernel<<<(NRtot + 255) / 256, 256, 0, stream>>>(partial_d, row_off, N, NRtot);
    scatter2_kernel<<<NR * NSL, 256, 0, stream>>>(src, dst, partial_d, csr_src, E);

    pack_w1t_kernel<<<(F_HID * F_IN) / 256, 256, 0, stream>>>(W1, W1t);

    gemm1_mfma_kernel<<<(N + 63) / 64, 256, 0, stream>>>(X, W1t, norm_src, h1b, N);

    spmm1_csr_kernel<<<(N + 7) / 8, 256, 0, stream>>>(h1b, row_off, csr_src, agg1, N);

    gemm2_kernel<<<(N + 63) / 64, 320, 0, stream>>>(agg1, W2, b1, norm_src, norm_dst, h2, N);

    spmm2_csr_kernel<<<(N + 15) / 16, 256, 0, stream>>>(h2, row_off, csr_src, norm_dst, b2, out, N);
}